// Round 2
// baseline (2817.144 us; speedup 1.0000x reference)
//
#include <hip/hip_runtime.h>
#include <math.h>

#define NG 76800
#define EG 307200
#define NL 38400
#define EL 153600
#define NB 64
#define NH 8

// ---------------- helpers ----------------
__device__ __forceinline__ unsigned enc_f(float x) {
    int i = __float_as_int(x);
    return (i >= 0) ? ((unsigned)i | 0x80000000u) : (unsigned)(~i);
}
__device__ __forceinline__ float dec_f(unsigned u) {
    int i = (u & 0x80000000u) ? (int)(u & 0x7FFFFFFFu) : (~(int)u);
    return __int_as_float(i);
}
__device__ __forceinline__ float sigmoidf(float x) { return 1.f / (1.f + expf(-x)); }

// ---------------- fp32 GEMM: C[M,Nsub] = A[M,K] @ W[K, c0:c0+Nsub] (+bias) ----------------
// W passed pre-offset by c0; ldw = full row stride of W. C stored compact (ldc=Nsub).
// 64x64 tile, 256 threads, 4x4 per thread, K <= 92 in one shot. M % 64 == 0.
__global__ __launch_bounds__(256) void gemm_kernel(const float* __restrict__ A,
                                                   const float* __restrict__ W, int ldw,
                                                   const float* __restrict__ bias,
                                                   float* __restrict__ C,
                                                   int M, int K, int Nsub) {
    __shared__ float At[96][68];
    __shared__ float Ws[96][64];
    const int m0 = blockIdx.x * 64;
    const int n0 = blockIdx.y * 64;
    const int tid = threadIdx.x;

    for (int idx = tid; idx < 64 * K; idx += 256) {
        int r = idx / K;
        int k = idx - r * K;
        At[k][r] = A[(size_t)(m0 + r) * K + k];
    }
    for (int idx = tid; idx < K * 64; idx += 256) {
        int k = idx >> 6;
        int c = idx & 63;
        int col = n0 + c;
        Ws[k][c] = (col < Nsub) ? W[(size_t)k * ldw + col] : 0.f;
    }
    __syncthreads();

    const int tx = tid & 15, ty = tid >> 4;
    float acc[4][4] = {};
    for (int k = 0; k < K; ++k) {
        float4 a4 = *(const float4*)&At[k][ty * 4];
        float4 w4 = *(const float4*)&Ws[k][tx * 4];
        float av[4] = {a4.x, a4.y, a4.z, a4.w};
        float wv[4] = {w4.x, w4.y, w4.z, w4.w};
#pragma unroll
        for (int i = 0; i < 4; ++i)
#pragma unroll
            for (int j = 0; j < 4; ++j) acc[i][j] += av[i] * wv[j];
    }
#pragma unroll
    for (int i = 0; i < 4; ++i) {
        int row = m0 + ty * 4 + i;
#pragma unroll
        for (int j = 0; j < 4; ++j) {
            int col = n0 + tx * 4 + j;
            if (col < Nsub) {
                float v = acc[i][j];
                if (bias) v += bias[col];
                C[(size_t)row * Nsub + col] = v;
            }
        }
    }
}

// ---------------- small transpose: Wt[N,K] = W[K,N] ----------------
__global__ __launch_bounds__(256) void transpose_kernel(const float* __restrict__ W,
                                                        float* __restrict__ Wt, int K, int N) {
    int idx = blockIdx.x * 256 + threadIdx.x;
    if (idx < K * N) {
        int k = idx / N;
        int c = idx - k * N;
        Wt[(size_t)c * K + k] = W[idx];
    }
}

// ---------------- edge scores (head-group chunked) ----------------
// lane = edge. Wt rows are wave-uniform scalar loads. Optional efB adds
// efB[e>>1] (the repeat(y2n,2) fusion). fsum accumulates head-summed f_out.
template <int FINE, int FE, bool WRITE_FSUM>
__global__ __launch_bounds__(256) void edge_score_kernel(
    const int* __restrict__ src, const int* __restrict__ dst,
    const float* __restrict__ efA,              // [E, FINE]
    const float* __restrict__ efB,              // [?, FINE] indexed e>>1, or null
    const float* __restrict__ Pni,              // [N, GH*FE] (edge bias folded in)
    const float* __restrict__ Pnj,              // [N, GH*FE]
    int GH,
    const float* __restrict__ Wt,               // rows c0.. : [GH*FE, FINE]
    const float* __restrict__ attn,             // offset by c0
    float* __restrict__ esc,                    // [E, GH]
    float* __restrict__ fsum,                   // [fsumE, FE] accumulated (+=)
    int E, int fsumE) {
    __shared__ float fsl[WRITE_FSUM ? 256 : 1][WRITE_FSUM ? (FE + 1) : 1];
    const int e = blockIdx.x * 256 + threadIdx.x;
    if (e >= E) return;
    const int t = threadIdx.x;
    if (WRITE_FSUM) {
        for (int f = 0; f < FE; ++f) fsl[t][f] = 0.f;
    }
    const int s = src[e], d = dst[e];
    float ef[FINE];
    if (efB) {
#pragma unroll
        for (int k = 0; k < FINE; ++k)
            ef[k] = efA[(size_t)e * FINE + k] + efB[(size_t)(e >> 1) * FINE + k];
    } else {
#pragma unroll
        for (int k = 0; k < FINE; ++k) ef[k] = efA[(size_t)e * FINE + k];
    }
    const float* pi = Pni + (size_t)s * GH * FE;
    const float* pj = Pnj + (size_t)d * GH * FE;

    for (int h = 0; h < GH; ++h) {
        float eh = 0.f;
        for (int f4 = 0; f4 < FE / 4; ++f4) {
            const int cb = h * FE + f4 * 4;
            float4 a4 = *(const float4*)&pi[cb];
            float4 b4 = *(const float4*)&pj[cb];
            float av[4] = {a4.x, a4.y, a4.z, a4.w};
            float bv[4] = {b4.x, b4.y, b4.z, b4.w};
#pragma unroll
            for (int fi = 0; fi < 4; ++fi) {
                const float* w = Wt + (size_t)(cb + fi) * FINE;
                float v = av[fi] + bv[fi];
#pragma unroll
                for (int k = 0; k < FINE; ++k) v += ef[k] * w[k];
                v = v > 0.f ? v : 0.01f * v;   // leaky_relu(0.01)
                eh += v * attn[cb + fi];
                if (WRITE_FSUM) fsl[t][f4 * 4 + fi] += v;
            }
        }
        esc[(size_t)e * GH + h] = eh;
    }
    if (WRITE_FSUM && e < fsumE) {
        for (int f = 0; f < FE; ++f) fsum[(size_t)e * FE + f] += fsl[t][f];
    }
}

// ---------------- edge softmax (per head-group) ----------------
__global__ __launch_bounds__(256) void seg_max_kernel(const float* __restrict__ esc,
                                                      const int* __restrict__ dst,
                                                      unsigned* __restrict__ maxEnc,
                                                      int E, int ghShift) {
    int i = blockIdx.x * 256 + threadIdx.x;
    if (i >= (E << ghShift)) return;
    int e = i >> ghShift, h = i & ((1 << ghShift) - 1);
    atomicMax(&maxEnc[((size_t)dst[e] << ghShift) + h], enc_f(esc[i]));
}

__global__ __launch_bounds__(256) void seg_exp_kernel(float* __restrict__ esc,
                                                      const int* __restrict__ dst,
                                                      const unsigned* __restrict__ maxEnc,
                                                      float* __restrict__ denom,
                                                      int E, int ghShift) {
    int i = blockIdx.x * 256 + threadIdx.x;
    if (i >= (E << ghShift)) return;
    int e = i >> ghShift, h = i & ((1 << ghShift) - 1);
    float m = dec_f(maxEnc[((size_t)dst[e] << ghShift) + h]);
    float ex = expf(esc[i] - m);
    esc[i] = ex;
    atomicAdd(&denom[((size_t)dst[e] << ghShift) + h], ex);
}

// ---------------- aggregation: out[d,f] += sum_h a_h * Pnode[s, h, f] ----------------
__global__ __launch_bounds__(256) void agg_kernel(const int* __restrict__ src,
                                                  const int* __restrict__ dst,
                                                  const float* __restrict__ ex,     // [E,GH]
                                                  const float* __restrict__ denom,  // [N,GH]
                                                  const float* __restrict__ Pnode,  // [N, GH*Fn]
                                                  float* __restrict__ outp,         // [N, Fn] zeroed
                                                  int E, int Fn, int GH) {
    const int wid = threadIdx.x >> 6;
    const int lane = threadIdx.x & 63;
    const int e = blockIdx.x * 4 + wid;
    if (e >= E) return;
    const int s = src[e], d = dst[e];
    float a[NH];
    for (int h = 0; h < GH; ++h)
        a[h] = ex[(size_t)e * GH + h] / denom[(size_t)d * GH + h];
    const float* pr = Pnode + (size_t)s * GH * Fn;
    for (int f = lane; f < Fn; f += 64) {
        float v = 0.f;
        for (int h = 0; h < GH; ++h) v += a[h] * pr[h * Fn + f];
        atomicAdd(&outp[(size_t)d * Fn + f], v);
    }
}

// ---------------- readout ----------------
__global__ __launch_bounds__(256) void readout_kernel(const float* __restrict__ nfb,   // [NL,92]
                                                      const float* __restrict__ y22p,  // [NG,36]
                                                      const float* __restrict__ Wr1,   // [128,128]
                                                      const float* __restrict__ br1,
                                                      const float* __restrict__ Wr2,   // [128]
                                                      const float* __restrict__ br2,
                                                      float* __restrict__ out) {
    const int b = blockIdx.x;
    const int t = threadIdx.x;
    __shared__ float y[128];
    __shared__ float hh[128];
    __shared__ float red[128];
    if (t < 92) {
        float s = 0.f;
        const float* base = nfb + (size_t)b * 600 * 92 + t;
        for (int i = 0; i < 600; ++i) s += base[(size_t)i * 92];
        y[t] = s * (1.f / 600.f);
    } else if (t >= 128 && t < 164) {
        int f = t - 128;
        float s = 0.f;
        const float* base = y22p + (size_t)b * 1200 * 36 + f;
        for (int i = 0; i < 1200; ++i) s += base[(size_t)i * 36];
        y[92 + f] = s * (1.f / 1200.f);
    }
    __syncthreads();
    if (t < 128) {
        float s = br1[t];
        for (int c = 0; c < 128; ++c) s += y[c] * Wr1[(size_t)c * 128 + t];
        hh[t] = sigmoidf(s);
    }
    __syncthreads();
    if (t < 128) red[t] = hh[t] * Wr2[t];
    __syncthreads();
    for (int k = 64; k > 0; k >>= 1) {
        if (t < k) red[t] += red[t + k];
        __syncthreads();
    }
    if (t == 0) out[b] = sigmoidf(red[0] + br2[0]);
}

// ---------------- host side ----------------
static inline int cdiv(int a, int b) { return (a + b - 1) / b; }

extern "C" void kernel_launch(void* const* d_in, const int* in_sizes, int n_in,
                              void* d_out, int out_size, void* d_ws, size_t ws_size,
                              hipStream_t stream) {
    const int* gg_src = (const int*)d_in[0];
    const int* gg_dst = (const int*)d_in[1];
    const float* gg_nf = (const float*)d_in[2];
    const float* gg_ef = (const float*)d_in[3];
    const int* lg_src = (const int*)d_in[4];
    const int* lg_dst = (const int*)d_in[5];
    const float* lg_nf = (const float*)d_in[6];
    const float* lg_ef = (const float*)d_in[7];
    const float* W_node1 = (const float*)d_in[8];
    const float* b_node1 = (const float*)d_in[9];
    const float* W_ni1 = (const float*)d_in[10];
    const float* W_nj1 = (const float*)d_in[11];
    const float* W_fij1 = (const float*)d_in[12];
    const float* attn1 = (const float*)d_in[13];
    const float* bias1 = (const float*)d_in[14];
    const float* W_node2a = (const float*)d_in[15];
    const float* b_node2a = (const float*)d_in[16];
    const float* W_ni2a = (const float*)d_in[17];
    const float* W_nj2a = (const float*)d_in[18];
    const float* W_fij2a = (const float*)d_in[19];
    const float* attn2a = (const float*)d_in[20];
    const float* bias2a = (const float*)d_in[21];
    const float* W_node2b = (const float*)d_in[22];
    const float* b_node2b = (const float*)d_in[23];
    const float* W_ni2b = (const float*)d_in[24];
    const float* W_nj2b = (const float*)d_in[25];
    const float* W_fij2b = (const float*)d_in[26];
    const float* attn2b = (const float*)d_in[27];
    const float* bias2b = (const float*)d_in[28];
    const float* Wr1 = (const float*)d_in[29];
    const float* br1 = (const float*)d_in[30];
    const float* Wr2 = (const float*)d_in[31];
    const float* br2 = (const float*)d_in[32];
    float* out = (float*)d_out;

    // ---- choose head-group size GH from ws_size (constant across calls) ----
    const size_t fixedB =
        ((size_t)NG * 40 * 4 + 255 & ~(size_t)255) +   // y2n
        ((size_t)NG * 36 * 4 + 255 & ~(size_t)255) +   // y22p
        ((size_t)NL * 92 * 4 + 255 & ~(size_t)255) +   // nfa
        ((size_t)EL * 40 * 4 + 255 & ~(size_t)255) +   // efa
        ((size_t)NL * 92 * 4 + 255 & ~(size_t)255) +   // nfb
        3 * ((size_t)320 * 40 * 4 + 255 & ~(size_t)255) + 4096;  // Wt's + slack
    const size_t perGH = (size_t)EG * 4              // esc per head
                       + 2 * (size_t)NG * 4          // maxE + den per head
                       + 2 * (size_t)NG * 36 * 4;    // slab unit (max chunk need per head)
    int GH = 1;
    for (int g = 8; g >= 1; g >>= 1) {
        if (fixedB + (size_t)g * perGH + ((size_t)64 << 10) <= ws_size) { GH = g; break; }
    }
    const int HG = NH / GH;
    const int ghShift = (GH == 8) ? 3 : (GH == 4) ? 2 : (GH == 2) ? 1 : 0;

    char* ws = (char*)d_ws;
    size_t off = 0;
    auto take = [&](size_t bytes) {
        size_t o = off;
        off += (bytes + 255) & ~(size_t)255;
        return (void*)(ws + o);
    };
    float* y2n = (float*)take((size_t)NG * 40 * 4);
    float* y22p = (float*)take((size_t)NG * 36 * 4);
    float* nfa = (float*)take((size_t)NL * 92 * 4);
    float* efa = (float*)take((size_t)EL * 40 * 4);
    float* nfb = (float*)take((size_t)NL * 92 * 4);
    float* Wt1 = (float*)take((size_t)288 * 10 * 4);
    float* Wt2a = (float*)take((size_t)320 * 40 * 4);
    float* Wt2b = (float*)take((size_t)320 * 40 * 4);
    float* esc = (float*)take((size_t)EG * GH * 4);
    unsigned* maxE = (unsigned*)take((size_t)NG * GH * 4);
    float* den = (float*)take((size_t)NG * GH * 4);
    float* slab = (float*)take(2 * (size_t)NG * GH * 36 * 4);

    auto gemm = [&](const float* A, const float* W, int ldw, const float* bias, float* C,
                    int M, int K, int Nsub) {
        dim3 grid(M / 64, cdiv(Nsub, 64));
        gemm_kernel<<<grid, 256, 0, stream>>>(A, W, ldw, bias, C, M, K, Nsub);
    };

    transpose_kernel<<<cdiv(10 * 288, 256), 256, 0, stream>>>(W_fij1, Wt1, 10, 288);
    transpose_kernel<<<cdiv(40 * 320, 256), 256, 0, stream>>>(W_fij2a, Wt2a, 40, 320);
    transpose_kernel<<<cdiv(40 * 320, 256), 256, 0, stream>>>(W_fij2b, Wt2b, 40, 320);

    // ---------------- stage 1 (gg) ----------------
    hipMemsetAsync(y2n, 0, (size_t)NG * 40 * 4, stream);
    hipMemsetAsync(y22p, 0, (size_t)NG * 36 * 4, stream);
    for (int g = 0; g < HG; ++g) {
        const int c0 = g * GH * 36;     // column offset in 288-wide projections
        const int c0n = g * GH * 40;    // column offset in 320-wide node proj
        hipMemsetAsync(maxE, 0, (size_t)NG * GH * 4, stream);
        hipMemsetAsync(den, 0, (size_t)NG * GH * 4, stream);
        float* Pni = slab;
        float* Pnj = slab + (size_t)NG * GH * 36;
        gemm(gg_nf, W_ni1 + c0, 288, bias1 + c0, Pni, NG, 40, GH * 36);
        gemm(gg_nf, W_nj1 + c0, 288, nullptr, Pnj, NG, 40, GH * 36);
        edge_score_kernel<10, 36, true><<<cdiv(EG, 256), 256, 0, stream>>>(
            gg_src, gg_dst, gg_ef, nullptr, Pni, Pnj, GH, Wt1 + (size_t)c0 * 10,
            attn1 + c0, esc, y22p, EG, NG);
        seg_max_kernel<<<cdiv(EG * GH, 256), 256, 0, stream>>>(esc, gg_dst, maxE, EG, ghShift);
        seg_exp_kernel<<<cdiv(EG * GH, 256), 256, 0, stream>>>(esc, gg_dst, maxE, den, EG, ghShift);
        float* Pnode = slab;   // alias: Pni/Pnj dead after edge_score
        gemm(gg_nf, W_node1 + c0n, 320, b_node1 + c0n, Pnode, NG, 40, GH * 40);
        agg_kernel<<<cdiv(EG, 4), 256, 0, stream>>>(gg_src, gg_dst, esc, den, Pnode, y2n, EG, 40, GH);
    }

    // ---------------- stage 2a (lg) ----------------
    hipMemsetAsync(nfa, 0, (size_t)NL * 92 * 4, stream);
    hipMemsetAsync(efa, 0, (size_t)EL * 40 * 4, stream);
    for (int g = 0; g < HG; ++g) {
        const int c0 = g * GH * 40;
        const int c0n = g * GH * 92;
        hipMemsetAsync(maxE, 0, (size_t)NL * GH * 4, stream);
        hipMemsetAsync(den, 0, (size_t)NL * GH * 4, stream);
        float* Pni = slab;
        float* Pnj = slab + (size_t)NL * GH * 40;
        gemm(lg_nf, W_ni2a + c0, 320, bias2a + c0, Pni, NL, 92, GH * 40);
        gemm(lg_nf, W_nj2a + c0, 320, nullptr, Pnj, NL, 92, GH * 40);
        edge_score_kernel<40, 40, true><<<cdiv(EL, 256), 256, 0, stream>>>(
            lg_src, lg_dst, lg_ef, y2n, Pni, Pnj, GH, Wt2a + (size_t)c0 * 40,
            attn2a + c0, esc, efa, EL, EL);
        seg_max_kernel<<<cdiv(EL * GH, 256), 256, 0, stream>>>(esc, lg_dst, maxE, EL, ghShift);
        seg_exp_kernel<<<cdiv(EL * GH, 256), 256, 0, stream>>>(esc, lg_dst, maxE, den, EL, ghShift);
        float* Pnode = slab;
        gemm(lg_nf, W_node2a + c0n, 736, b_node2a + c0n, Pnode, NL, 92, GH * 92);
        agg_kernel<<<cdiv(EL, 4), 256, 0, stream>>>(lg_src, lg_dst, esc, den, Pnode, nfa, EL, 92, GH);
    }

    // ---------------- stage 2b (lg) ----------------
    hipMemsetAsync(nfb, 0, (size_t)NL * 92 * 4, stream);
    for (int g = 0; g < HG; ++g) {
        const int c0 = g * GH * 40;
        const int c0n = g * GH * 92;
        hipMemsetAsync(maxE, 0, (size_t)NL * GH * 4, stream);
        hipMemsetAsync(den, 0, (size_t)NL * GH * 4, stream);
        float* Pni = slab;
        float* Pnj = slab + (size_t)NL * GH * 40;
        gemm(nfa, W_ni2b + c0, 320, bias2b + c0, Pni, NL, 92, GH * 40);
        gemm(nfa, W_nj2b + c0, 320, nullptr, Pnj, NL, 92, GH * 40);
        edge_score_kernel<40, 40, false><<<cdiv(EL, 256), 256, 0, stream>>>(
            lg_src, lg_dst, efa, nullptr, Pni, Pnj, GH, Wt2b + (size_t)c0 * 40,
            attn2b + c0, esc, nullptr, EL, 0);
        seg_max_kernel<<<cdiv(EL * GH, 256), 256, 0, stream>>>(esc, lg_dst, maxE, EL, ghShift);
        seg_exp_kernel<<<cdiv(EL * GH, 256), 256, 0, stream>>>(esc, lg_dst, maxE, den, EL, ghShift);
        float* Pnode = slab;
        gemm(nfa, W_node2b + c0n, 736, b_node2b + c0n, Pnode, NL, 92, GH * 92);
        agg_kernel<<<cdiv(EL, 4), 256, 0, stream>>>(lg_src, lg_dst, esc, den, Pnode, nfb, EL, 92, GH);
    }

    // ---------------- readout ----------------
    readout_kernel<<<NB, 256, 0, stream>>>(nfb, y22p, Wr1, br1, Wr2, br2, out);
}

// Round 3
// 2537.269 us; speedup vs baseline: 1.1103x; 1.1103x over previous
//
#include <hip/hip_runtime.h>
#include <math.h>

#define NG 76800
#define EG 307200
#define NL 38400
#define EL 153600
#define NB 64
#define NH 8

// ---------------- helpers ----------------
__device__ __forceinline__ unsigned enc_f(float x) {
    int i = __float_as_int(x);
    return (i >= 0) ? ((unsigned)i | 0x80000000u) : (unsigned)(~i);
}
__device__ __forceinline__ float dec_f(unsigned u) {
    int i = (u & 0x80000000u) ? (int)(u & 0x7FFFFFFFu) : (~(int)u);
    return __int_as_float(i);
}
__device__ __forceinline__ float sigmoidf(float x) { return 1.f / (1.f + expf(-x)); }

// ---------------- fp32 GEMM: C[M,Nsub] = A[M,K] @ W[K, c0:c0+Nsub] (+bias) ----------------
__global__ __launch_bounds__(256) void gemm_kernel(const float* __restrict__ A,
                                                   const float* __restrict__ W, int ldw,
                                                   const float* __restrict__ bias,
                                                   float* __restrict__ C,
                                                   int M, int K, int Nsub) {
    __shared__ float At[96][68];
    __shared__ float Ws[96][64];
    const int m0 = blockIdx.x * 64;
    const int n0 = blockIdx.y * 64;
    const int tid = threadIdx.x;

    for (int idx = tid; idx < 64 * K; idx += 256) {
        int r = idx / K;
        int k = idx - r * K;
        At[k][r] = A[(size_t)(m0 + r) * K + k];
    }
    for (int idx = tid; idx < K * 64; idx += 256) {
        int k = idx >> 6;
        int c = idx & 63;
        int col = n0 + c;
        Ws[k][c] = (col < Nsub) ? W[(size_t)k * ldw + col] : 0.f;
    }
    __syncthreads();

    const int tx = tid & 15, ty = tid >> 4;
    float acc[4][4] = {};
    for (int k = 0; k < K; ++k) {
        float4 a4 = *(const float4*)&At[k][ty * 4];
        float4 w4 = *(const float4*)&Ws[k][tx * 4];
        float av[4] = {a4.x, a4.y, a4.z, a4.w};
        float wv[4] = {w4.x, w4.y, w4.z, w4.w};
#pragma unroll
        for (int i = 0; i < 4; ++i)
#pragma unroll
            for (int j = 0; j < 4; ++j) acc[i][j] += av[i] * wv[j];
    }
#pragma unroll
    for (int i = 0; i < 4; ++i) {
        int row = m0 + ty * 4 + i;
#pragma unroll
        for (int j = 0; j < 4; ++j) {
            int col = n0 + tx * 4 + j;
            if (col < Nsub) {
                float v = acc[i][j];
                if (bias) v += bias[col];
                C[(size_t)row * Nsub + col] = v;
            }
        }
    }
}

// ---------------- small transpose: Wt[N,K] = W[K,N] ----------------
__global__ __launch_bounds__(256) void transpose_kernel(const float* __restrict__ W,
                                                        float* __restrict__ Wt, int K, int N) {
    int idx = blockIdx.x * 256 + threadIdx.x;
    if (idx < K * N) {
        int k = idx / N;
        int c = idx - k * N;
        Wt[(size_t)c * K + k] = W[idx];
    }
}

// ---------------- edge scores: wave-per-edge ----------------
// One wave owns one edge. 64 lanes split the GH*FE columns: L=64/GH lanes per
// head; lane lam in a head handles cnt (=ceil/floor FE/L) CONSECUTIVE columns.
// Row gathers of Pni[src]/Pnj[dst] are wave-cooperative (whole row -> L1).
// Wt (transposed W_fij) staged in LDS, read as aligned float4.
// eh: shfl_xor reduce within head; fsum (head-summed f_out): shfl_xor across heads.
template <int FINE, int FE, bool WRITE_FSUM>
__global__ __launch_bounds__(256) void edge_score_kernel(
    const int* __restrict__ src, const int* __restrict__ dst,
    const float* __restrict__ efA,              // [E, FINE]
    const float* __restrict__ efB,              // [?, FINE] indexed e>>1, or null
    const float* __restrict__ Pni,              // [N, GH*FE] (edge bias folded in)
    const float* __restrict__ Pnj,              // [N, GH*FE]
    int GH,
    const float* __restrict__ Wt,               // [GH*FE, FINE], group-offset
    const float* __restrict__ attn,             // group-offset; index by column c
    float* __restrict__ esc,                    // [E, GH]
    float* __restrict__ fsum,                   // [fsumE, FE] accumulated (+=)
    int E, int fsumE) {
    constexpr int WTS = (FINE == 10) ? 12 : 44;  // row stride (floats), 16B-aligned rows
    __shared__ float wt_s[8 * FE][WTS];
    const int rows = GH * FE;
    for (int idx = threadIdx.x; idx < rows * FINE; idx += 256) {
        int r = idx / FINE, k = idx - r * FINE;
        wt_s[r][k] = Wt[idx];
    }
    __syncthreads();

    const int lane = threadIdx.x & 63;
    const int L = 64 / GH;              // lanes per head
    const int h = lane / L;
    const int lam = lane - h * L;
    const int q = FE / L, rr = FE - q * L;
    const int cnt = (lam < rr) ? q + 1 : q;
    const int f0 = lam * q + (lam < rr ? lam : rr);
    const int cbase = h * FE + f0;

    float attn_r[5];
#pragma unroll
    for (int j = 0; j < 5; ++j) attn_r[j] = (j < cnt) ? attn[cbase + j] : 0.f;

    const int nwaves = gridDim.x << 2;
    for (int e = (blockIdx.x << 2) + (threadIdx.x >> 6); e < E; e += nwaves) {
        const int s = src[e], d = dst[e];
        float efr[FINE];
#pragma unroll
        for (int k = 0; k < FINE; ++k) efr[k] = efA[(size_t)e * FINE + k];
        if (efB) {
#pragma unroll
            for (int k = 0; k < FINE; ++k) efr[k] += efB[(size_t)(e >> 1) * FINE + k];
        }
        const float* pi = Pni + (size_t)s * rows;
        const float* pj = Pnj + (size_t)d * rows;

        float vj[5];
        float eh = 0.f;
#pragma unroll
        for (int j = 0; j < 5; ++j) {
            vj[j] = 0.f;
            if (j < cnt) {
                const int c = cbase + j;
                float v = pi[c] + pj[c];
#pragma unroll
                for (int k4 = 0; k4 < FINE / 4; ++k4) {
                    float4 w4 = *(const float4*)&wt_s[c][k4 * 4];
                    v += efr[k4 * 4 + 0] * w4.x + efr[k4 * 4 + 1] * w4.y +
                         efr[k4 * 4 + 2] * w4.z + efr[k4 * 4 + 3] * w4.w;
                }
#pragma unroll
                for (int k = (FINE / 4) * 4; k < FINE; ++k) v += efr[k] * wt_s[c][k];
                v = v > 0.f ? v : 0.01f * v;   // leaky_relu(0.01)
                eh += v * attn_r[j];
                vj[j] = v;
            }
        }
        // esc: reduce within head (lanes lam=0..L-1 are consecutive)
        for (int m = 1; m < L; m <<= 1) eh += __shfl_xor(eh, m, 64);
        if (lam == 0) esc[(size_t)e * GH + h] = eh;
        // fsum: reduce across heads (stride-L lane groups share the same f-range)
        if (WRITE_FSUM && e < fsumE) {
#pragma unroll
            for (int j = 0; j < 5; ++j) {
                float vs = vj[j];
                for (int m = L; m < 64; m <<= 1) vs += __shfl_xor(vs, m, 64);
                if (h == 0 && j < cnt) fsum[(size_t)e * FE + f0 + j] += vs;
            }
        }
    }
}

// ---------------- edge softmax (per head-group) ----------------
__global__ __launch_bounds__(256) void seg_max_kernel(const float* __restrict__ esc,
                                                      const int* __restrict__ dst,
                                                      unsigned* __restrict__ maxEnc,
                                                      int E, int ghShift) {
    int i = blockIdx.x * 256 + threadIdx.x;
    if (i >= (E << ghShift)) return;
    int e = i >> ghShift, h = i & ((1 << ghShift) - 1);
    atomicMax(&maxEnc[((size_t)dst[e] << ghShift) + h], enc_f(esc[i]));
}

__global__ __launch_bounds__(256) void seg_exp_kernel(float* __restrict__ esc,
                                                      const int* __restrict__ dst,
                                                      const unsigned* __restrict__ maxEnc,
                                                      float* __restrict__ denom,
                                                      int E, int ghShift) {
    int i = blockIdx.x * 256 + threadIdx.x;
    if (i >= (E << ghShift)) return;
    int e = i >> ghShift, h = i & ((1 << ghShift) - 1);
    float m = dec_f(maxEnc[((size_t)dst[e] << ghShift) + h]);
    float ex = expf(esc[i] - m);
    esc[i] = ex;
    atomicAdd(&denom[((size_t)dst[e] << ghShift) + h], ex);
}

// ---------------- aggregation: out[d,f] += sum_h a_h * Pnode[s, h, f] ----------------
__global__ __launch_bounds__(256) void agg_kernel(const int* __restrict__ src,
                                                  const int* __restrict__ dst,
                                                  const float* __restrict__ ex,     // [E,GH]
                                                  const float* __restrict__ denom,  // [N,GH]
                                                  const float* __restrict__ Pnode,  // [N, GH*Fn]
                                                  float* __restrict__ outp,         // [N, Fn] zeroed
                                                  int E, int Fn, int GH) {
    const int wid = threadIdx.x >> 6;
    const int lane = threadIdx.x & 63;
    const int e = blockIdx.x * 4 + wid;
    if (e >= E) return;
    const int s = src[e], d = dst[e];
    float a[NH];
    for (int h = 0; h < GH; ++h)
        a[h] = ex[(size_t)e * GH + h] / denom[(size_t)d * GH + h];
    const float* pr = Pnode + (size_t)s * GH * Fn;
    for (int f = lane; f < Fn; f += 64) {
        float v = 0.f;
        for (int h = 0; h < GH; ++h) v += a[h] * pr[h * Fn + f];
        atomicAdd(&outp[(size_t)d * Fn + f], v);
    }
}

// ---------------- readout ----------------
__global__ __launch_bounds__(256) void readout_kernel(const float* __restrict__ nfb,   // [NL,92]
                                                      const float* __restrict__ y22p,  // [NG,36]
                                                      const float* __restrict__ Wr1,   // [128,128]
                                                      const float* __restrict__ br1,
                                                      const float* __restrict__ Wr2,   // [128]
                                                      const float* __restrict__ br2,
                                                      float* __restrict__ out) {
    const int b = blockIdx.x;
    const int t = threadIdx.x;
    __shared__ float y[128];
    __shared__ float hh[128];
    __shared__ float red[128];
    if (t < 92) {
        float s = 0.f;
        const float* base = nfb + (size_t)b * 600 * 92 + t;
        for (int i = 0; i < 600; ++i) s += base[(size_t)i * 92];
        y[t] = s * (1.f / 600.f);
    } else if (t >= 128 && t < 164) {
        int f = t - 128;
        float s = 0.f;
        const float* base = y22p + (size_t)b * 1200 * 36 + f;
        for (int i = 0; i < 1200; ++i) s += base[(size_t)i * 36];
        y[92 + f] = s * (1.f / 1200.f);
    }
    __syncthreads();
    if (t < 128) {
        float s = br1[t];
        for (int c = 0; c < 128; ++c) s += y[c] * Wr1[(size_t)c * 128 + t];
        hh[t] = sigmoidf(s);
    }
    __syncthreads();
    if (t < 128) red[t] = hh[t] * Wr2[t];
    __syncthreads();
    for (int k = 64; k > 0; k >>= 1) {
        if (t < k) red[t] += red[t + k];
        __syncthreads();
    }
    if (t == 0) out[b] = sigmoidf(red[0] + br2[0]);
}

// ---------------- host side ----------------
static inline int cdiv(int a, int b) { return (a + b - 1) / b; }

extern "C" void kernel_launch(void* const* d_in, const int* in_sizes, int n_in,
                              void* d_out, int out_size, void* d_ws, size_t ws_size,
                              hipStream_t stream) {
    const int* gg_src = (const int*)d_in[0];
    const int* gg_dst = (const int*)d_in[1];
    const float* gg_nf = (const float*)d_in[2];
    const float* gg_ef = (const float*)d_in[3];
    const int* lg_src = (const int*)d_in[4];
    const int* lg_dst = (const int*)d_in[5];
    const float* lg_nf = (const float*)d_in[6];
    const float* lg_ef = (const float*)d_in[7];
    const float* W_node1 = (const float*)d_in[8];
    const float* b_node1 = (const float*)d_in[9];
    const float* W_ni1 = (const float*)d_in[10];
    const float* W_nj1 = (const float*)d_in[11];
    const float* W_fij1 = (const float*)d_in[12];
    const float* attn1 = (const float*)d_in[13];
    const float* bias1 = (const float*)d_in[14];
    const float* W_node2a = (const float*)d_in[15];
    const float* b_node2a = (const float*)d_in[16];
    const float* W_ni2a = (const float*)d_in[17];
    const float* W_nj2a = (const float*)d_in[18];
    const float* W_fij2a = (const float*)d_in[19];
    const float* attn2a = (const float*)d_in[20];
    const float* bias2a = (const float*)d_in[21];
    const float* W_node2b = (const float*)d_in[22];
    const float* b_node2b = (const float*)d_in[23];
    const float* W_ni2b = (const float*)d_in[24];
    const float* W_nj2b = (const float*)d_in[25];
    const float* W_fij2b = (const float*)d_in[26];
    const float* attn2b = (const float*)d_in[27];
    const float* bias2b = (const float*)d_in[28];
    const float* Wr1 = (const float*)d_in[29];
    const float* br1 = (const float*)d_in[30];
    const float* Wr2 = (const float*)d_in[31];
    const float* br2 = (const float*)d_in[32];
    float* out = (float*)d_out;

    // ---- choose head-group size GH from ws_size (constant across calls) ----
    const size_t fixedB =
        ((size_t)NG * 40 * 4 + 255 & ~(size_t)255) +   // y2n
        ((size_t)NG * 36 * 4 + 255 & ~(size_t)255) +   // y22p
        ((size_t)NL * 92 * 4 + 255 & ~(size_t)255) +   // nfa
        ((size_t)EL * 40 * 4 + 255 & ~(size_t)255) +   // efa
        ((size_t)NL * 92 * 4 + 255 & ~(size_t)255) +   // nfb
        3 * ((size_t)320 * 40 * 4 + 255 & ~(size_t)255) + 4096;  // Wt's + slack
    const size_t perGH = (size_t)EG * 4              // esc per head
                       + 2 * (size_t)NG * 4          // maxE + den per head
                       + 2 * (size_t)NG * 36 * 4;    // slab unit (max chunk need per head)
    int GH = 1;
    for (int g = 8; g >= 1; g >>= 1) {
        if (fixedB + (size_t)g * perGH + ((size_t)64 << 10) <= ws_size) { GH = g; break; }
    }
    const int HG = NH / GH;
    const int ghShift = (GH == 8) ? 3 : (GH == 4) ? 2 : (GH == 2) ? 1 : 0;

    char* ws = (char*)d_ws;
    size_t off = 0;
    auto take = [&](size_t bytes) {
        size_t o = off;
        off += (bytes + 255) & ~(size_t)255;
        return (void*)(ws + o);
    };
    float* y2n = (float*)take((size_t)NG * 40 * 4);
    float* y22p = (float*)take((size_t)NG * 36 * 4);
    float* nfa = (float*)take((size_t)NL * 92 * 4);
    float* efa = (float*)take((size_t)EL * 40 * 4);
    float* nfb = (float*)take((size_t)NL * 92 * 4);
    float* Wt1 = (float*)take((size_t)288 * 10 * 4);
    float* Wt2a = (float*)take((size_t)320 * 40 * 4);
    float* Wt2b = (float*)take((size_t)320 * 40 * 4);
    float* esc = (float*)take((size_t)EG * GH * 4);
    unsigned* maxE = (unsigned*)take((size_t)NG * GH * 4);
    float* den = (float*)take((size_t)NG * GH * 4);
    float* slab = (float*)take(2 * (size_t)NG * GH * 36 * 4);

    auto gemm = [&](const float* A, const float* W, int ldw, const float* bias, float* C,
                    int M, int K, int Nsub) {
        dim3 grid(M / 64, cdiv(Nsub, 64));
        gemm_kernel<<<grid, 256, 0, stream>>>(A, W, ldw, bias, C, M, K, Nsub);
    };

    transpose_kernel<<<cdiv(10 * 288, 256), 256, 0, stream>>>(W_fij1, Wt1, 10, 288);
    transpose_kernel<<<cdiv(40 * 320, 256), 256, 0, stream>>>(W_fij2a, Wt2a, 40, 320);
    transpose_kernel<<<cdiv(40 * 320, 256), 256, 0, stream>>>(W_fij2b, Wt2b, 40, 320);

    const int EBLK = 1024;   // edge-kernel blocks (4 waves each, grid-stride over edges)

    // ---------------- stage 1 (gg) ----------------
    hipMemsetAsync(y2n, 0, (size_t)NG * 40 * 4, stream);
    hipMemsetAsync(y22p, 0, (size_t)NG * 36 * 4, stream);
    for (int g = 0; g < HG; ++g) {
        const int c0 = g * GH * 36;
        const int c0n = g * GH * 40;
        hipMemsetAsync(maxE, 0, (size_t)NG * GH * 4, stream);
        hipMemsetAsync(den, 0, (size_t)NG * GH * 4, stream);
        float* Pni = slab;
        float* Pnj = slab + (size_t)NG * GH * 36;
        gemm(gg_nf, W_ni1 + c0, 288, bias1 + c0, Pni, NG, 40, GH * 36);
        gemm(gg_nf, W_nj1 + c0, 288, nullptr, Pnj, NG, 40, GH * 36);
        edge_score_kernel<10, 36, true><<<EBLK, 256, 0, stream>>>(
            gg_src, gg_dst, gg_ef, nullptr, Pni, Pnj, GH, Wt1 + (size_t)c0 * 10,
            attn1 + c0, esc, y22p, EG, NG);
        seg_max_kernel<<<cdiv(EG * GH, 256), 256, 0, stream>>>(esc, gg_dst, maxE, EG, ghShift);
        seg_exp_kernel<<<cdiv(EG * GH, 256), 256, 0, stream>>>(esc, gg_dst, maxE, den, EG, ghShift);
        float* Pnode = slab;   // alias: Pni/Pnj dead after edge_score
        gemm(gg_nf, W_node1 + c0n, 320, b_node1 + c0n, Pnode, NG, 40, GH * 40);
        agg_kernel<<<cdiv(EG, 4), 256, 0, stream>>>(gg_src, gg_dst, esc, den, Pnode, y2n, EG, 40, GH);
    }

    // ---------------- stage 2a (lg) ----------------
    hipMemsetAsync(nfa, 0, (size_t)NL * 92 * 4, stream);
    hipMemsetAsync(efa, 0, (size_t)EL * 40 * 4, stream);
    for (int g = 0; g < HG; ++g) {
        const int c0 = g * GH * 40;
        const int c0n = g * GH * 92;
        hipMemsetAsync(maxE, 0, (size_t)NL * GH * 4, stream);
        hipMemsetAsync(den, 0, (size_t)NL * GH * 4, stream);
        float* Pni = slab;
        float* Pnj = slab + (size_t)NL * GH * 40;
        gemm(lg_nf, W_ni2a + c0, 320, bias2a + c0, Pni, NL, 92, GH * 40);
        gemm(lg_nf, W_nj2a + c0, 320, nullptr, Pnj, NL, 92, GH * 40);
        edge_score_kernel<40, 40, true><<<EBLK, 256, 0, stream>>>(
            lg_src, lg_dst, lg_ef, y2n, Pni, Pnj, GH, Wt2a + (size_t)c0 * 40,
            attn2a + c0, esc, efa, EL, EL);
        seg_max_kernel<<<cdiv(EL * GH, 256), 256, 0, stream>>>(esc, lg_dst, maxE, EL, ghShift);
        seg_exp_kernel<<<cdiv(EL * GH, 256), 256, 0, stream>>>(esc, lg_dst, maxE, den, EL, ghShift);
        float* Pnode = slab;
        gemm(lg_nf, W_node2a + c0n, 736, b_node2a + c0n, Pnode, NL, 92, GH * 92);
        agg_kernel<<<cdiv(EL, 4), 256, 0, stream>>>(lg_src, lg_dst, esc, den, Pnode, nfa, EL, 92, GH);
    }

    // ---------------- stage 2b (lg) ----------------
    hipMemsetAsync(nfb, 0, (size_t)NL * 92 * 4, stream);
    for (int g = 0; g < HG; ++g) {
        const int c0 = g * GH * 40;
        const int c0n = g * GH * 92;
        hipMemsetAsync(maxE, 0, (size_t)NL * GH * 4, stream);
        hipMemsetAsync(den, 0, (size_t)NL * GH * 4, stream);
        float* Pni = slab;
        float* Pnj = slab + (size_t)NL * GH * 40;
        gemm(nfa, W_ni2b + c0, 320, bias2b + c0, Pni, NL, 92, GH * 40);
        gemm(nfa, W_nj2b + c0, 320, nullptr, Pnj, NL, 92, GH * 40);
        edge_score_kernel<40, 40, false><<<EBLK, 256, 0, stream>>>(
            lg_src, lg_dst, efa, nullptr, Pni, Pnj, GH, Wt2b + (size_t)c0 * 40,
            attn2b + c0, esc, nullptr, EL, 0);
        seg_max_kernel<<<cdiv(EL * GH, 256), 256, 0, stream>>>(esc, lg_dst, maxE, EL, ghShift);
        seg_exp_kernel<<<cdiv(EL * GH, 256), 256, 0, stream>>>(esc, lg_dst, maxE, den, EL, ghShift);
        float* Pnode = slab;
        gemm(nfa, W_node2b + c0n, 736, b_node2b + c0n, Pnode, NL, 92, GH * 92);
        agg_kernel<<<cdiv(EL, 4), 256, 0, stream>>>(lg_src, lg_dst, esc, den, Pnode, nfb, EL, 92, GH);
    }

    // ---------------- readout ----------------
    readout_kernel<<<NB, 256, 0, stream>>>(nfb, y22p, Wr1, br1, Wr2, br2, out);
}